// Round 16
// baseline (509.850 us; speedup 1.0000x reference)
//
#include <hip/hip_runtime.h>

// Problem constants
#define Bb 32
#define Cc 512
#define Ll 4096
#define Hh 8
#define Dd 64
#define Gg 32
#define BLt (Bb * Ll)          // 131072 rows
#define NKV 520                // 512 v cols + 8 logit cols (fallback layout)
#define NKVPAD 640

typedef __attribute__((ext_vector_type(4))) float f32x4;
typedef __attribute__((ext_vector_type(8))) short short8;
typedef __attribute__((ext_vector_type(4))) short s16x4;
typedef __attribute__((ext_vector_type(4))) int int4v;

union U16 { int4v v; short s[8]; };

__device__ __forceinline__ float bf2f(short s) {
    unsigned u = ((unsigned)(unsigned short)s) << 16;
    float f; __builtin_memcpy(&f, &u, 4); return f;
}
__device__ __forceinline__ short f2bf(float f) {
    unsigned u; __builtin_memcpy(&u, &f, 4);
    u = (u + 0x7FFFu + ((u >> 16) & 1u)) >> 16;
    return (short)u;
}

// packed-k position within a row: per 32-k block, 16B chunk f holds
// {k=f*4..f*4+3, k=16+f*4..16+f*4+3}  (MFMA 16x16x32 A/B fragment order)
__device__ __forceinline__ int kpack(int k) {
    int blk = k >> 5, r = k & 31;
    return blk * 32 + ((r & 15) >> 2) * 8 + ((r >> 4) << 2) + (r & 3);
}

// LDS tile swizzle (128-B rows): chunk ^= row&7, applied on write (via global src
// pre-permute or explicit ds_write addr) and on read.
__device__ __forceinline__ int swz_off(int row, int inner) {
    return row * 128 + (inner ^ ((row & 7) << 4));
}

__device__ __forceinline__ void gload16(const short* g, short* l) {
    __builtin_amdgcn_global_load_lds((const __attribute__((address_space(1))) unsigned int*)g,
                                     (__attribute__((address_space(3))) unsigned int*)l,
                                     16, 0, 0);
}
__device__ __forceinline__ void gload16f(const float* g, float* l) {
    __builtin_amdgcn_global_load_lds((const __attribute__((address_space(1))) unsigned int*)g,
                                     (__attribute__((address_space(3))) unsigned int*)l,
                                     16, 0, 0);
}

#define BAR() __builtin_amdgcn_s_barrier()
#define SFENCE() __builtin_amdgcn_sched_barrier(0)

// ---------------- prep: fold weights ----------------
__global__ void k_prep(const float* __restrict__ Wk, const float* __restrict__ Wv,
                       const float* __restrict__ Wo, const float* __restrict__ q,
                       short* __restrict__ Wct, short* __restrict__ Wot, int packWo)
{
    int bid = blockIdx.x, t = threadIdx.x;
    if (bid < NKVPAD) {
        int n = bid;
        if (n < 512) {
            for (int k = t; k < 512; k += 64)
                Wct[n * 512 + kpack(k)] = f2bf(Wv[k * 512 + n]);
        } else if (n < NKV) {
            int h = n - 512;
            for (int k = t; k < 512; k += 64) {
                float acc = 0.f;
                for (int d = 0; d < 64; ++d)
                    acc += Wk[k * 512 + h * 64 + d] * q[h * 64 + d];
                Wct[n * 512 + kpack(k)] = f2bf(acc * 0.125f);   // 1/sqrt(64)
            }
        } else {
            for (int k = t; k < 512; k += 64) Wct[n * 512 + kpack(k)] = 0;
        }
    } else {
        int c = bid - NKVPAD;
        for (int k = t; k < 512; k += 64)
            Wot[c * 512 + (packWo ? kpack(k) : k)] = f2bf(Wo[k * 512 + c]);
    }
}

// ---- fused GroupNorm stats + normalize + transpose -> hT (packed-k) ----
// block = (b, 64-c range) = 4 GN groups x full L. GRID MUST BE 256 (32 b x 8 c).
__launch_bounds__(256)
__global__ void k_gnormf(const float* __restrict__ x, const float* __restrict__ gamma,
                         const float* __restrict__ beta, short* __restrict__ hT)
{
    __shared__ float tile[64 * 65];
    __shared__ float redS[4][4], redQ[4][4];   // [wave][g4]
    __shared__ float ascale[64], bshift[64];

    const int bid = blockIdx.x;
    const int b = bid >> 3, c0 = (bid & 7) * 64;
    const int t = threadIdx.x;
    const int lane = t & 63, w = t >> 6;

    float s[4] = {0.f, 0.f, 0.f, 0.f}, ss[4] = {0.f, 0.f, 0.f, 0.f};
    #pragma unroll
    for (int g4 = 0; g4 < 4; ++g4) {
        #pragma unroll 1
        for (int rr = 0; rr < 16; ++rr) {
            const float* rp = x + ((size_t)b << 21) + ((size_t)(c0 + g4 * 16 + rr) << 12);
            #pragma unroll
            for (int it = 0; it < 4; ++it) {
                f32x4 v = *(const f32x4*)(rp + (it * 256 + t) * 4);
                s[g4]  += v[0] + v[1] + v[2] + v[3];
                ss[g4] += v[0]*v[0] + v[1]*v[1] + v[2]*v[2] + v[3]*v[3];
            }
        }
    }
    #pragma unroll
    for (int g4 = 0; g4 < 4; ++g4)
        for (int o = 32; o > 0; o >>= 1) {
            s[g4]  += __shfl_down(s[g4], o);
            ss[g4] += __shfl_down(ss[g4], o);
        }
    if (lane == 0) {
        #pragma unroll
        for (int g4 = 0; g4 < 4; ++g4) { redS[w][g4] = s[g4]; redQ[w][g4] = ss[g4]; }
    }
    __syncthreads();
    if (t < 4) {                              // t = g4
        float S = redS[0][t] + redS[1][t] + redS[2][t] + redS[3][t];
        float Q = redQ[0][t] + redQ[1][t] + redQ[2][t] + redQ[3][t];
        float mean = S * (1.0f / 65536.0f);
        float var  = Q * (1.0f / 65536.0f) - mean * mean;
        redS[0][t] = mean;
        redQ[0][t] = rsqrtf(var + 1e-5f);
    }
    __syncthreads();
    if (t < 64) {
        int g4 = t >> 4;
        float a = redQ[0][g4] * gamma[c0 + t];
        ascale[t] = a;
        bshift[t] = beta[c0 + t] - redS[0][g4] * a;
    }
    __syncthreads();

    const int lq = t & 15, cqq = t >> 4;
    const int ll = t >> 2, cq4 = t & 3;
    #pragma unroll 1
    for (int lt = 0; lt < 64; ++lt) {
        int l0 = lt * 64;
        #pragma unroll
        for (int p = 0; p < 4; ++p) {
            int cl = cqq + p * 16;
            float a = ascale[cl], bb = bshift[cl];
            f32x4 v = *(const f32x4*)(x + ((size_t)b << 21) + ((size_t)(c0 + cl) << 12) + l0 + lq * 4);
            #pragma unroll
            for (int j = 0; j < 4; ++j) tile[cl * 65 + lq * 4 + j] = v[j] * a + bb;
        }
        __syncthreads();
        int bl = b * Ll + l0 + ll;
        short hbuf[16];
        #pragma unroll
        for (int j = 0; j < 16; ++j) hbuf[j] = f2bf(tile[(cq4 * 16 + j) * 65 + ll]);
        short* dst = hT + (size_t)bl * 512 + ((c0 >> 5) + (cq4 >> 1)) * 32 + ((cq4 & 1) << 2);
        #pragma unroll
        for (int jj = 0; jj < 4; ++jj) {
            s16x4 v4 = { hbuf[jj*4+0], hbuf[jj*4+1], hbuf[jj*4+2], hbuf[jj*4+3] };
            *(s16x4*)(dst + jj * 8) = v4;
        }
        __syncthreads();
    }
}

// ---------------- GroupNorm stats (fallback path) ----------------
__global__ void k_stats(const float* __restrict__ x, float* __restrict__ stats)
{
    int bg = blockIdx.x;                     // b*32 + g ; contiguous 65536 floats
    const float* p = x + (size_t)bg * 65536;
    int t = threadIdx.x;
    float s = 0.f, ss = 0.f;
    for (int i = t * 4; i < 65536; i += 1024) {
        f32x4 v = *(const f32x4*)(p + i);
        s  += v[0] + v[1] + v[2] + v[3];
        ss += v[0]*v[0] + v[1]*v[1] + v[2]*v[2] + v[3]*v[3];
    }
    for (int o = 32; o > 0; o >>= 1) { s += __shfl_down(s, o); ss += __shfl_down(ss, o); }
    __shared__ float red[8];
    int lane = t & 63, w = t >> 6;
    if (lane == 0) { red[w] = s; red[4 + w] = ss; }
    __syncthreads();
    if (t == 0) {
        float S  = red[0] + red[1] + red[2] + red[3];
        float SS = red[4] + red[5] + red[6] + red[7];
        float mean = S * (1.0f / 65536.0f);
        float var  = SS * (1.0f / 65536.0f) - mean * mean;
        stats[bg * 2]     = mean;
        stats[bg * 2 + 1] = rsqrtf(var + 1e-5f);
    }
}

// ------- normalize + transpose (fallback path) -------
__global__ void k_norm_t(const float* __restrict__ x, const float* __restrict__ gamma,
                         const float* __restrict__ beta, const float* __restrict__ stats,
                         short* __restrict__ hT)
{
    __shared__ float tile[64 * 65];
    int b = blockIdx.z, c0 = blockIdx.y * 64, l0 = blockIdx.x * 64;
    int t = threadIdx.x;
    int lq = t & 15, cq = t >> 4;
    #pragma unroll
    for (int p = 0; p < 4; ++p) {
        int cl = cq + p * 16;
        int c = c0 + cl;
        float mean = stats[(b * 32 + (c >> 4)) * 2];
        float rstd = stats[(b * 32 + (c >> 4)) * 2 + 1];
        float a  = rstd * gamma[c];
        float bb = beta[c] - mean * a;
        f32x4 v = *(const f32x4*)(x + ((size_t)b << 21) + ((size_t)c << 12) + l0 + lq * 4);
        #pragma unroll
        for (int j = 0; j < 4; ++j) tile[cl * 65 + lq * 4 + j] = v[j] * a + bb;
    }
    __syncthreads();
    int ll = t >> 2, cq4 = t & 3;
    int bl = b * Ll + l0 + ll;
    short hbuf[16];
    #pragma unroll
    for (int j = 0; j < 16; ++j) hbuf[j] = f2bf(tile[(cq4 * 16 + j) * 65 + ll]);
    short* dst = hT + (size_t)bl * 512 + ((c0 >> 5) + (cq4 >> 1)) * 32 + ((cq4 & 1) << 2);
    #pragma unroll
    for (int jj = 0; jj < 4; ++jj) {
        s16x4 v4 = { hbuf[jj*4+0], hbuf[jj*4+1], hbuf[jj*4+2], hbuf[jj*4+3] };
        *(s16x4*)(dst + jj * 8) = v4;
    }
}

// ---------------- GEMM1 (flattened + fused logits, logits only in ntile==0) ----------------
__launch_bounds__(256, 2)
__global__ void k_gemm1f(const short* __restrict__ A, const short* __restrict__ Bw,
                         short* __restrict__ vbuf, short* __restrict__ lbuf)
{
    __shared__ short sA[2][8192];
    __shared__ short sB[2][8192];
    __shared__ short wqlds[8192];          // 16 rows x 512 k (rows 8-15 zero)
    const int t = threadIdx.x;
    const int nwg = 1024;
    const int bid = blockIdx.x;
    const int work = (bid & 7) * (nwg >> 3) + (bid >> 3);
    const int ntile = work & 3;
    const int n0 = ntile * 128;
    const int mbase = (work >> 2) * 512;

    const int lane = t & 63, wid = t >> 6;
    const int wm = wid >> 1, wn = wid & 1;
    const int g = lane >> 4, ln = lane & 15;

    // ---- preload wq panel (Wct rows 512..519) into LDS, swizzled ----
    {
        int row = t >> 5;                  // 0..7
        int cp = (t & 31) * 2;             // 16B-chunk index, +0/+1
        int4v v0 = *(const int4v*)(Bw + (size_t)(512 + row) * 512 + cp * 8);
        int4v v1 = *(const int4v*)(Bw + (size_t)(512 + row) * 512 + cp * 8 + 8);
        *(int4v*)((char*)wqlds + row * 1024 + ((cp * 16) ^ ((row & 7) << 4))) = v0;
        *(int4v*)((char*)wqlds + row * 1024 + (((cp + 1) * 16) ^ ((row & 7) << 4))) = v1;
        int4v z = {0, 0, 0, 0};
        int row2 = 8 + (t >> 5);
        *(int4v*)((char*)wqlds + row2 * 1024 + ((cp * 16) ^ ((row2 & 7) << 4))) = z;
        *(int4v*)((char*)wqlds + row2 * 1024 + (((cp + 1) * 16) ^ ((row2 & 7) << 4))) = z;
    }
    asm volatile("s_waitcnt vmcnt(0) lgkmcnt(0)" ::: "memory");
    BAR(); SFENCE();

    const int srow = wid * 8 + (lane >> 3);
    const int sinner = (((lane & 7) ^ ((lane >> 3) & 7)) << 3);
    const short* gAs = A  + (size_t)(mbase + srow) * 512 + sinner;
    const short* gBs = Bw + (size_t)(n0 + srow) * 512 + sinner;

    f32x4 acc[4][4] = {};
    f32x4 accq[4] = {};

    auto stage = [&](int kt, int buf) {
        size_t offA = (size_t)(kt >> 3) * 65536 + (size_t)(kt & 7) * 64;
        size_t offB = (size_t)(kt & 7) * 64;
        #pragma unroll
        for (int gq = 0; gq < 4; ++gq) {
            gload16(gAs + (size_t)gq * 32 * 512 + offA, &sA[buf][gq * 2048 + wid * 512]);
            gload16(gBs + (size_t)gq * 32 * 512 + offB, &sB[buf][gq * 2048 + wid * 512]);
        }
    };
    auto compute = [&](int buf, int kk) {
        #pragma unroll
        for (int ks = 0; ks < 2; ++ks) {
            short8 af[4], bfr[4];
            #pragma unroll
            for (int i = 0; i < 4; ++i) {
                af[i]  = *(const short8*)((const char*)&sA[buf][0] + swz_off(wm * 64 + i * 16 + ln, ks * 64 + g * 16));
                bfr[i] = *(const short8*)((const char*)&sB[buf][0] + swz_off(wn * 64 + i * 16 + ln, ks * 64 + g * 16));
            }
            #pragma unroll
            for (int mi = 0; mi < 4; ++mi)
                #pragma unroll
                for (int ni = 0; ni < 4; ++ni)
                    acc[mi][ni] = __builtin_amdgcn_mfma_f32_16x16x32_bf16(af[mi], bfr[ni], acc[mi][ni], 0, 0, 0);
            if (ntile == 0) {               // block-uniform: logits only where used
                short8 bq = *(const short8*)((const char*)wqlds + ln * 1024 +
                                      ((kk * 128 + ks * 64 + g * 16) ^ ((ln & 7) << 4)));
                #pragma unroll
                for (int mi = 0; mi < 4; ++mi)
                    accq[mi] = __builtin_amdgcn_mfma_f32_16x16x32_bf16(af[mi], bq, accq[mi], 0, 0, 0);
            }
        }
    };

    stage(0, 0); stage(1, 1);
    #pragma unroll 1
    for (int s = 0; s < 32; ++s) {
        if (s == 31)           asm volatile("s_waitcnt vmcnt(0)"  ::: "memory");
        else if ((s & 7) == 0 && s) asm volatile("s_waitcnt vmcnt(16)" ::: "memory");
        else                   asm volatile("s_waitcnt vmcnt(8)"  ::: "memory");
        BAR(); SFENCE();
        compute(s & 1, s & 7);
        SFENCE();
        if ((s & 7) == 7) {
            BAR();
            int m0 = mbase + (s >> 3) * 128;
            {
                short* scrW = &sB[s & 1][0] + wid * 2048;   // 4 KB per wave
                const int blkq = (lane & 7) >> 2, jq = lane & 3;
                #pragma unroll
                for (int p = 0; p < 2; ++p) {
                    #pragma unroll
                    for (int mh = 0; mh < 2; ++mh)
                        #pragma unroll
                        for (int ni = 0; ni < 4; ++ni)
                            #pragma unroll
                            for (int i = 0; i < 4; ++i)
                                scrW[(mh * 16 + g * 4 + i) * 64 + ni * 16 + ln] = f2bf(acc[p * 2 + mh][ni][i]);
                    asm volatile("s_waitcnt lgkmcnt(0)" ::: "memory"); SFENCE();
                    #pragma unroll
                    for (int it = 0; it < 4; ++it) {
                        int mrl = it * 8 + (lane >> 3);
                        const short* bp = scrW + mrl * 64 + blkq * 32;
                        s16x4 lo = *(const s16x4*)(bp + 4 * jq);
                        s16x4 hi = *(const s16x4*)(bp + 16 + 4 * jq);
                        union { int4v v; s16x4 h[2]; } ov;
                        ov.h[0] = lo; ov.h[1] = hi;
                        int m = m0 + wm * 64 + p * 32 + mrl;
                        int nc = n0 + wn * 64 + blkq * 32 + jq * 8;
                        *(int4v*)(vbuf + (size_t)m * 512 + nc) = ov.v;
                    }
                    asm volatile("s_waitcnt lgkmcnt(0)" ::: "memory"); SFENCE();
                }
            }
            if (ntile == 0 && wn == 0 && ln < 8) {
                #pragma unroll
                for (int mi = 0; mi < 4; ++mi)
                    #pragma unroll
                    for (int i = 0; i < 4; ++i) {
                        int m = m0 + wm * 64 + mi * 16 + g * 4 + i;
                        lbuf[(size_t)m * 8 + ln] = f2bf(accq[mi][i]);
                    }
            }
            #pragma unroll
            for (int mi = 0; mi < 4; ++mi) {
                #pragma unroll
                for (int ni = 0; ni < 4; ++ni)
                    acc[mi][ni] = (f32x4){0.f, 0.f, 0.f, 0.f};
                accq[mi] = (f32x4){0.f, 0.f, 0.f, 0.f};
            }
        }
        if (s < 30) { BAR(); stage(s + 2, s & 1); SFENCE(); }
    }
}

// ------- attn weights from lbuf: attnW[bl*32 + h*4 + j] = softmax_j -------
__global__ void k_attnw2(const short* __restrict__ lbuf, const float* __restrict__ rpe,
                         float* __restrict__ attnW)
{
    int tid = blockIdx.x * 256 + threadIdx.x;
    int bl = tid >> 3, h = tid & 7;
    int l = bl & (Ll - 1);
    float lg0 = (l > 0)      ? bf2f(lbuf[(size_t)(bl - 1) * 8 + h]) + rpe[h * 3 + 0] : -1e30f;
    float lg1 =                bf2f(lbuf[(size_t)bl * 8 + h])       + rpe[h * 3 + 1];
    float lg2 = (l < Ll - 1) ? bf2f(lbuf[(size_t)(bl + 1) * 8 + h]) + rpe[h * 3 + 2] : -1e30f;
    float m = fmaxf(lg1, fmaxf(lg0, lg2));
    float e0 = (l > 0)      ? __expf(lg0 - m) : 0.f;
    float e1 =                __expf(lg1 - m);
    float e2 = (l < Ll - 1) ? __expf(lg2 - m) : 0.f;
    float inv = 1.0f / (e0 + e1 + e2);
    f32x4 w = { e0 * inv, e1 * inv, e2 * inv, 0.0f };
    *(f32x4*)(attnW + (size_t)bl * 32 + h * 4) = w;
}

// ------- GEMM2 (flattened, FUSED combine, single-R early-reload pipeline) -------
// combineStep uses truncating pair-pack f32->bf16 (3 VALU/pair vs ~8 RNE).
__launch_bounds__(256, 2)
__global__ void k_gemm2f(const short* __restrict__ Wot, const short* __restrict__ vbuf,
                         const float* __restrict__ attnW, const float* __restrict__ x,
                         float* __restrict__ out)
{
    __shared__ short sA[2][8192];
    __shared__ short sBc[2][8192];
    __shared__ float wlds[4096];           // 128 rows x 8 hslots x 16B = 16 KB
    const int t = threadIdx.x;
    const int nwg = 1024;
    const int bid = blockIdx.x;
    const int work = (bid & 7) * (nwg >> 3) + (bid >> 3);
    const int n0 = work * 128;             // bl tile (fixed per block)

    const int lane = t & 63, wid = t >> 6;
    const int wm = wid >> 1, wn = wid & 1;
    const int g = lane >> 4, ln = lane & 15;

    const int srow = wid * 8 + (lane >> 3);                      // 0..31
    const int sinner = (((lane & 7) ^ ((lane >> 3) & 7)) << 3);  // shorts
    const short* gAs = Wot + (size_t)srow * 512 + sinner;

    // per-thread 3-row byte offsets for the 4 dest rows
    unsigned ovm[4], ov0[4], ovp[4];
    #pragma unroll
    for (int q2 = 0; q2 < 4; ++q2) {
        int r = n0 + srow + 32 * q2;
        int l = r & (Ll - 1);
        int rm = (l == 0) ? r : r - 1;
        int rp = (l == Ll - 1) ? r : r + 1;
        ov0[q2] = (unsigned)r  * 1024u + (unsigned)sinner * 2u;
        ovm[q2] = (unsigned)rm * 1024u + (unsigned)sinner * 2u;
        ovp[q2] = (unsigned)rp * 1024u + (unsigned)sinner * 2u;
    }
    const char* vb = (const char*)vbuf;

    // epilogue geometry
    const int r4 = lane >> 4, lcm = (lane & 15) * 4;
    const int ngE = n0 + wn * 64 + lcm;
    const size_t rowbase = ((size_t)(ngE >> 12) << 21) + (size_t)(ngE & (Ll - 1));
    const float* xrow = x + rowbase;
    float* outrow = out + rowbase;

    f32x4 acc[4][4] = {};
    U16 Rm[4], R0[4], Rp[4];       // single R set, reloaded right after consumption

    auto stageA = [&](int s, int buf) {
        size_t off = (size_t)(s >> 3) * 65536 + (size_t)(s & 7) * 64;
        #pragma unroll
        for (int gq = 0; gq < 4; ++gq)
            gload16(gAs + (size_t)gq * 32 * 512 + off, &sA[buf][gq * 2048 + wid * 512]);
    };
    auto loadR = [&](int s1) {
        unsigned off = (unsigned)(s1 & 7) * 128u;      // bytes
        #pragma unroll
        for (int q2 = 0; q2 < 4; ++q2) {
            Rm[q2].v = *(const int4v*)(vb + ovm[q2] + off);
            R0[q2].v = *(const int4v*)(vb + ov0[q2] + off);
            Rp[q2].v = *(const int4v*)(vb + ovp[q2] + off);
        }
    };
    auto combineStep = [&](int s1, int buf) {
        int h = s1 & 7;
        #pragma unroll
        for (int q2 = 0; q2 < 4; ++q2) {
            int r = srow + 32 * q2;
            f32x4 w = *(const f32x4*)&wlds[r * 32 + ((h ^ (r & 7)) << 2)];
            int4v cmv;
            #pragma unroll
            for (int jj = 0; jj < 4; ++jj) {
                float oa = w[0] * bf2f(Rm[q2].s[2 * jj])     + w[1] * bf2f(R0[q2].s[2 * jj])
                         + w[2] * bf2f(Rp[q2].s[2 * jj]);
                float ob = w[0] * bf2f(Rm[q2].s[2 * jj + 1]) + w[1] * bf2f(R0[q2].s[2 * jj + 1])
                         + w[2] * bf2f(Rp[q2].s[2 * jj + 1]);
                unsigned ua, ub;
                __builtin_memcpy(&ua, &oa, 4);
                __builtin_memcpy(&ub, &ob, 4);
                cmv[jj] = (int)((ub & 0xFFFF0000u) | (ua >> 16));   // truncating pack
            }
            *(int4v*)((char*)&sBc[buf][0] + q2 * 4096 + wid * 1024 + lane * 16) = cmv;
        }
    };
    auto compute = [&](int buf) {
        #pragma unroll
        for (int ks = 0; ks < 2; ++ks) {
            short8 af[4], bfr[4];
            #pragma unroll
            for (int i = 0; i < 4; ++i) {
                af[i]  = *(const short8*)((const char*)&sA[buf][0] + swz_off(wm * 64 + i * 16 + ln, ks * 64 + g * 16));
                bfr[i] = *(const short8*)((const char*)&sBc[buf][0] + swz_off(wn * 64 + i * 16 + ln, ks * 64 + g * 16));
            }
            #pragma unroll
            for (int mi = 0; mi < 4; ++mi)
                #pragma unroll
                for (int ni = 0; ni < 4; ++ni)
                    acc[mi][ni] = __builtin_amdgcn_mfma_f32_16x16x32_bf16(af[mi], bfr[ni], acc[mi][ni], 0, 0, 0);
        }
    };
    auto epilogue = [&](int s) {
        BAR();                                              // all waves done with sA[s&1]
        float* scr = (float*)((char*)&sA[s & 1][0] + wid * 4096);   // 16r x 64c f32
        int m0c = (s >> 3) * 128;
        #pragma unroll
        for (int p = 0; p < 4; ++p) {
            #pragma unroll
            for (int ni = 0; ni < 4; ++ni)
                #pragma unroll
                for (int i = 0; i < 4; ++i) {
                    int r = g * 4 + i;
                    int col = (ni * 16 + ln) ^ ((((r & 3) ^ (r >> 2)) & 3) << 4);
                    scr[r * 64 + col] = acc[p][ni][i];
                }
            asm volatile("s_waitcnt lgkmcnt(0)" ::: "memory"); SFENCE();
            #pragma unroll
            for (int j = 0; j < 4; ++j) {
                int rr = r4 + 4 * j;
                int cst = lcm ^ ((((rr & 3) ^ (rr >> 2)) & 3) << 4);
                f32x4 sv = *(const f32x4*)&scr[rr * 64 + cst];
                int c = m0c + wm * 64 + p * 16 + rr;
                f32x4 xv = *(const f32x4*)(xrow + ((size_t)c << 12));
                *(f32x4*)(outrow + ((size_t)c << 12)) = xv + sv;
            }
            asm volatile("s_waitcnt lgkmcnt(0)" ::: "memory"); SFENCE();
        }
        #pragma unroll
        for (int mi = 0; mi < 4; ++mi)
            #pragma unroll
            for (int ni = 0; ni < 4; ++ni)
                acc[mi][ni] = (f32x4){0.f, 0.f, 0.f, 0.f};
    };

    // ---- prologue: A(0),A(1),weights,R(0); drain; combine(0); R(1) ----
    stageA(0, 0); stageA(1, 1);
    {
        const float* wsrc = attnW + (size_t)n0 * 32;
        int rr = lane >> 3, hl = lane & 7;
        #pragma unroll
        for (int j = 0; j < 4; ++j) {
            int row = (wid * 4 + j) * 8 + rr;
            gload16f(wsrc + row * 32 + ((hl ^ (row & 7)) << 2), &wlds[(wid * 4 + j) * 256]);
        }
    }
    loadR(0); SFENCE();
    asm volatile("s_waitcnt vmcnt(0)" ::: "memory");
    BAR(); SFENCE();
    combineStep(0, 0);
    asm volatile("s_waitcnt lgkmcnt(0)" ::: "memory"); SFENCE();
    loadR(1); SFENCE();

    #pragma unroll 1
    for (int s = 0; s < 32; ++s) {
        // top wait: need loadR(s+1) (mid step s-1) + stageA(s) (tail s-2).
        // Leave outstanding: stageA(s+1)[4] (+ epilogue 32 VM if s%8==0).
        if (s == 0 || s == 31)       asm volatile("s_waitcnt vmcnt(0)"  ::: "memory");
        else if ((s & 7) == 0)       asm volatile("s_waitcnt vmcnt(36)" ::: "memory");
        else                         asm volatile("s_waitcnt vmcnt(4)"  ::: "memory");
        BAR(); SFENCE();
        if (s < 31) {
            combineStep(s + 1, (s + 1) & 1);      // consume R(s+1)
            SFENCE();
            if (s < 30) { loadR(s + 2); SFENCE(); }   // reload same set, full-step flight
        }
        compute(s & 1);
        asm volatile("s_waitcnt lgkmcnt(0)" ::: "memory"); SFENCE();
        if ((s & 7) == 7) epilogue(s);
        if (s < 30) { BAR(); stageA(s + 2, s & 1); SFENCE(); }
    }
}

// ---------------- fallback path (ws too small; round-2-proven) ----------------
__launch_bounds__(256, 2)
__global__ void k_gemm1_fb(const short* __restrict__ A, const short* __restrict__ Bw,
                           short* __restrict__ kv)
{
    __shared__ short sA[2][8192];
    __shared__ short sB[2][8192];
    const int t = threadIdx.x;
    const int m0 = blockIdx.y * 128;
    const int n0 = blockIdx.x * 128;
    const int lane = t & 63, wid = t >> 6;
    const int wm = wid >> 1, wn = wid & 1;
    const int g = lane >> 4, ln = lane & 15;

    const int srow = wid * 8 + (lane >> 3);
    const int sinner = (((lane & 7) ^ ((lane >> 3) & 7)) << 3);
    const short* gAs = A  + (size_t)(m0 + srow) * 512 + sinner;
    const short* gBs = Bw + (size_t)(n0 + srow) * 512 + sinner;

    f32x4 acc[4][4] = {};

    auto stage = [&](int kt, int buf) {
        #pragma unroll
        for (int gq = 0; gq < 4; ++gq) {
            gload16(gAs + (size_t)gq * 32 * 512 + kt * 64, &sA[buf][gq * 2048 + wid * 512]);
            gload16(gBs + (size_t)gq * 32 * 512 + kt * 64, &sB[buf][gq * 2048 + wid * 512]);
        }
    };
    auto compute = [&](int buf) {
        #pragma unroll
        for (int ks = 0; ks < 2; ++ks) {
            short8 af[4], bfr[4];
            #pragma unroll
            for (int i = 0; i < 4; ++i) {
                af[i]  = *(const short8*)((const char*)&sA[buf][0] + swz_off(wm * 64 + i * 16 + ln, ks * 64 + g * 16));
                bfr[i] = *(const short8*)((const char*)&sB[buf][0] + swz_off(wn * 64 + i * 16 + ln, ks * 64 + g * 16));
            }
            #pragma unroll
            for (int mi = 0; mi < 4; ++mi)
                #pragma unroll
                for (int ni = 0; ni < 4; ++ni)
                    acc[mi][ni] = __builtin_amdgcn_mfma_f32_16x16x32_bf16(af[mi], bfr[ni], acc[mi][ni], 0, 0, 0);
        }
    };

    stage(0, 0);
    __syncthreads();
    #pragma unroll 1
    for (int kt = 0; kt < 8; ++kt) {
        if (kt < 7) stage(kt + 1, (kt + 1) & 1);
        compute(kt & 1);
        __syncthreads();
    }

    #pragma unroll
    for (int mi = 0; mi < 4; ++mi)
        #pragma unroll
        for (int ni = 0; ni < 4; ++ni) {
            int n = n0 + wn * 64 + ni * 16 + ln;
            if (n < NKV) {
                #pragma unroll
                for (int i = 0; i < 4; ++i) {
                    int m = m0 + wm * 64 + mi * 16 + g * 4 + i;
                    kv[(size_t)m * NKV + n] = f2bf(acc[mi][ni][i]);
                }
            }
        }
}

__global__ void k_attnw(const short* __restrict__ kv, const float* __restrict__ rpe,
                        float* __restrict__ attnW)
{
    int tid = blockIdx.x * 256 + threadIdx.x;
    int bl = tid >> 3, h = tid & 7;
    int l = bl & (Ll - 1);
    float lg[3];
    #pragma unroll
    for (int j = 0; j < 3; ++j) {
        bool valid = (j == 1) || (j == 0 && l > 0) || (j == 2 && l < Ll - 1);
        lg[j] = valid ? (bf2f(kv[(size_t)(bl + j - 1) * NKV + 512 + h]) + rpe[h * 3 + j])
                      : -1e30f;
    }
    float m = fmaxf(lg[0], fmaxf(lg[1], lg[2]));
    float e0 = __expf(lg[0] - m), e1 = __expf(lg[1] - m), e2 = __expf(lg[2] - m);
    float inv = 1.0f / (e0 + e1 + e2);
    f32x4 w = { e0 * inv, e1 * inv, e2 * inv, 0.0f };
    *(f32x4*)(attnW + (size_t)bl * 32 + h * 4) = w;
}

__launch_bounds__(256, 2)
__global__ void k_gemm2_fused(const short* __restrict__ Wot, const short* __restrict__ kv,
                              const float* __restrict__ attnW, const float* __restrict__ x,
                              float* __restrict__ out)
{
    __shared__ short sA[2][8192];
    __shared__ short sB[2][8192];
    const int t = threadIdx.x;
    const int m0 = blockIdx.x * 128;
    const int n0 = blockIdx.y * 128;
    const int lane = t & 63, wid = t >> 6;
    const int wm = wid >> 1, wn = wid & 1;
    const int g = lane >> 4, ln = lane & 15;
    const int sr = t >> 1, ksh = t & 1;

    const short* gA = Wot + (size_t)(m0 + sr) * 512 + ksh * 32;
    const int nrow = n0 + sr;
    const int lpos = nrow & (Ll - 1);
    const int nm1 = (lpos == 0) ? nrow : nrow - 1;
    const int np1 = (lpos == Ll - 1) ? nrow : nrow + 1;
    const short* gV0 = kv + (size_t)nrow * NKV + ksh * 32;
    const short* gVm = kv + (size_t)nm1  * NKV + ksh * 32;
    const short* gVp = kv + (size_t)np1  * NKV + ksh * 32;
    const float* gW = attnW + (size_t)nrow * 32;

    f32x4 acc[4][4] = {};
    U16 ra[4], rbm[4], rb0[4], rbp[4];
    f32x4 wv;

    auto load_tile = [&](int kt) {
        #pragma unroll
        for (int qq = 0; qq < 4; ++qq) {
            ra[qq].v  = *(const int4v*)(gA  + kt * 64 + qq * 8);
            rbm[qq].v = *(const int4v*)(gVm + kt * 64 + qq * 8);
            rb0[qq].v = *(const int4v*)(gV0 + kt * 64 + qq * 8);
            rbp[qq].v = *(const int4v*)(gVp + kt * 64 + qq * 8);
        }
        wv = *(const f32x4*)(gW + kt * 4);
    };
    auto write_tile = [&](int buf) {
        short ob[32];
        #pragma unroll
        for (int qq = 0; qq < 4; ++qq)
            #pragma unroll
            for (int j = 0; j < 8; ++j) {
                float o = wv[0] * bf2f(rbm[qq].s[j]) + wv[1] * bf2f(rb0[qq].s[j])
                        + wv[2] * bf2f(rbp[qq].s[j]);
                ob[qq * 8 + j] = f2bf(o);
            }
        #pragma unroll
        for (int f = 0; f < 4; ++f) {
            U16 wa, wb;
            #pragma unroll
            for (int j = 0; j < 4; ++j) {
                wa.s[j]     = ra[f >> 1].s[(f & 1) * 4 + j];
                wa.s[4 + j] = ra[2 + (f >> 1)].s[(f & 1) * 4 + j];
                wb.s[j]     = ob[4 * f + j];
                wb.s[4 + j] = ob[16 + 4 * f + j];
            }
            int off = swz_off(sr, ksh * 64 + f * 16);
            *(int4v*)((char*)&sA[buf][0] + off) = wa.v;
            *(int4v*)((char*)&sB[buf][0] + off) = wb.v;
        }
    };
    auto compute = [&](int buf) {
        #pragma unroll
        for (int ks = 0; ks < 2; ++ks) {
            short8 af[4], bfr[4];
            #pragma unroll
            for (int i = 0; i < 4; ++i) {
                af[i]  = *(const short8*)((const char*)&sA[buf][0] + swz_off(wm * 64 + i * 16 + ln, ks * 64 + g * 16));
                bfr[i] = *(const short8*)((const char*)&sB[buf][0] + swz_off(wn * 64 + i * 16 + ln, ks * 64 + g * 16));
            }
            #pragma unroll
            for (int mi = 0; mi < 4; ++mi)
                #pragma unroll
                for (int ni = 0; ni < 4; ++ni)
                    acc[mi][ni] = __builtin_amdgcn_mfma_f32_16x16x32_bf16(af[mi], bfr[ni], acc[mi][ni], 0, 0, 0);
        }
    };

    load_tile(0); write_tile(0); __syncthreads();
    #pragma unroll 1
    for (int kt = 0; kt < 8; ++kt) {
        if (kt < 7) load_tile(kt + 1);
        compute(kt & 1);
        if (kt < 7) write_tile((kt + 1) & 1);
        __syncthreads();
    }

    #pragma unroll
    for (int mi = 0; mi < 4; ++mi)
        #pragma unroll
        for (int ni = 0; ni < 4; ++ni)
            #pragma unroll
            for (int i = 0; i < 4; ++i) {
                int c = m0 + wm * 64 + mi * 16 + g * 4 + i;
                int ng = n0 + wn * 64 + ni * 16 + ln;
                int b = ng >> 12, l = ng & (Ll - 1);
                size_t off = ((size_t)b << 21) | ((size_t)c << 12) | (size_t)l;
                out[off] = x[off] + acc[mi][ni][i];
            }
}

// ---------------- launcher ----------------
extern "C" void kernel_launch(void* const* d_in, const int* in_sizes, int n_in,
                              void* d_out, int out_size, void* d_ws, size_t ws_size,
                              hipStream_t stream)
{
    const float* x     = (const float*)d_in[0];
    const float* gamma = (const float*)d_in[1];
    const float* beta  = (const float*)d_in[2];
    const float* Wk    = (const float*)d_in[3];
    const float* Wv    = (const float*)d_in[4];
    const float* Wo    = (const float*)d_in[5];
    const float* q     = (const float*)d_in[6];
    const float* rpe   = (const float*)d_in[7];
    float* out = (float*)d_out;
    char* ws = (char*)d_ws;

    const size_t MB128 = 134217728ull;
    const size_t MAIN_WS = MB128 * 2 + 655360 + 524288 + 2097152 + 8192;

    if (ws_size >= MAIN_WS) {
        float* attnW = (float*)(ws);                       // 16 MB (in old obuf slot)
        short* vbuf  = (short*)(ws + MB128);
        short* Wct   = (short*)(ws + 2 * MB128);
        short* Wot   = (short*)(ws + 2 * MB128 + 655360);
        short* lbuf  = (short*)(ws + 2 * MB128 + 655360 + 524288);
        short* hT    = (short*)d_out;          // scratch until gemm1 done

        k_prep<<<1152, 64, 0, stream>>>(Wk, Wv, Wo, q, Wct, Wot, 1);
        k_gnormf<<<256, 256, 0, stream>>>(x, gamma, beta, hT);
        k_gemm1f<<<1024, 256, 0, stream>>>(hT, Wct, vbuf, lbuf);
        k_attnw2<<<4096, 256, 0, stream>>>(lbuf, rpe, attnW);
        k_gemm2f<<<1024, 256, 0, stream>>>(Wot, vbuf, attnW, x, out);
    } else {
        short* Wct   = (short*)(ws + 0);
        short* Wot   = (short*)(ws + 655360);
        float* stats = (float*)(ws + 1179648);
        float* attnW = (float*)(ws + 1187840);
        short* kv    = (short*)(ws + 17965056);
        short* hT    = (short*)d_out;

        k_prep<<<1152, 64, 0, stream>>>(Wk, Wv, Wo, q, Wct, Wot, 0);
        k_stats<<<1024, 256, 0, stream>>>(x, stats);
        k_norm_t<<<dim3(64, 8, 32), 256, 0, stream>>>(x, gamma, beta, stats, hT);
        k_gemm1_fb<<<dim3(5, 1024), 256, 0, stream>>>(hT, Wct, kv);
        k_attnw<<<4096, 256, 0, stream>>>(kv, rpe, attnW);
        k_gemm2_fused<<<dim3(4, 1024), 256, 0, stream>>>(Wot, kv, attnW, x, out);
    }
}

// Round 17
// 501.456 us; speedup vs baseline: 1.0167x; 1.0167x over previous
//
#include <hip/hip_runtime.h>

// Problem constants
#define Bb 32
#define Cc 512
#define Ll 4096
#define Hh 8
#define Dd 64
#define Gg 32
#define BLt (Bb * Ll)          // 131072 rows
#define NKV 520                // 512 v cols + 8 logit cols (fallback layout)
#define NKVPAD 640

typedef __attribute__((ext_vector_type(4))) float f32x4;
typedef __attribute__((ext_vector_type(8))) short short8;
typedef __attribute__((ext_vector_type(4))) short s16x4;
typedef __attribute__((ext_vector_type(4))) int int4v;

union U16 { int4v v; short s[8]; };

__device__ __forceinline__ float bf2f(short s) {
    unsigned u = ((unsigned)(unsigned short)s) << 16;
    float f; __builtin_memcpy(&f, &u, 4); return f;
}
__device__ __forceinline__ short f2bf(float f) {
    unsigned u; __builtin_memcpy(&u, &f, 4);
    u = (u + 0x7FFFu + ((u >> 16) & 1u)) >> 16;
    return (short)u;
}

// packed-k position within a row: per 32-k block, 16B chunk f holds
// {k=f*4..f*4+3, k=16+f*4..16+f*4+3}  (MFMA 16x16x32 A/B fragment order)
__device__ __forceinline__ int kpack(int k) {
    int blk = k >> 5, r = k & 31;
    return blk * 32 + ((r & 15) >> 2) * 8 + ((r >> 4) << 2) + (r & 3);
}

// LDS tile swizzle (128-B rows): chunk ^= row&7, applied on write (via global src
// pre-permute or explicit ds_write addr) and on read.
__device__ __forceinline__ int swz_off(int row, int inner) {
    return row * 128 + (inner ^ ((row & 7) << 4));
}

__device__ __forceinline__ void gload16(const short* g, short* l) {
    __builtin_amdgcn_global_load_lds((const __attribute__((address_space(1))) unsigned int*)g,
                                     (__attribute__((address_space(3))) unsigned int*)l,
                                     16, 0, 0);
}
__device__ __forceinline__ void gload16f(const float* g, float* l) {
    __builtin_amdgcn_global_load_lds((const __attribute__((address_space(1))) unsigned int*)g,
                                     (__attribute__((address_space(3))) unsigned int*)l,
                                     16, 0, 0);
}

#define BAR() __builtin_amdgcn_s_barrier()
#define SFENCE() __builtin_amdgcn_sched_barrier(0)

// ---------------- prep: fold weights ----------------
__global__ void k_prep(const float* __restrict__ Wk, const float* __restrict__ Wv,
                       const float* __restrict__ Wo, const float* __restrict__ q,
                       short* __restrict__ Wct, short* __restrict__ Wot, int packWo)
{
    int bid = blockIdx.x, t = threadIdx.x;
    if (bid < NKVPAD) {
        int n = bid;
        if (n < 512) {
            for (int k = t; k < 512; k += 64)
                Wct[n * 512 + kpack(k)] = f2bf(Wv[k * 512 + n]);
        } else if (n < NKV) {
            int h = n - 512;
            for (int k = t; k < 512; k += 64) {
                float acc = 0.f;
                for (int d = 0; d < 64; ++d)
                    acc += Wk[k * 512 + h * 64 + d] * q[h * 64 + d];
                Wct[n * 512 + kpack(k)] = f2bf(acc * 0.125f);   // 1/sqrt(64)
            }
        } else {
            for (int k = t; k < 512; k += 64) Wct[n * 512 + kpack(k)] = 0;
        }
    } else {
        int c = bid - NKVPAD;
        for (int k = t; k < 512; k += 64)
            Wot[c * 512 + (packWo ? kpack(k) : k)] = f2bf(Wo[k * 512 + c]);
    }
}

// ---------------- GroupNorm stats ----------------
__global__ void k_stats(const float* __restrict__ x, float* __restrict__ stats)
{
    int bg = blockIdx.x;                     // b*32 + g ; contiguous 65536 floats
    const float* p = x + (size_t)bg * 65536;
    int t = threadIdx.x;
    float s = 0.f, ss = 0.f;
    for (int i = t * 4; i < 65536; i += 1024) {
        f32x4 v = *(const f32x4*)(p + i);
        s  += v[0] + v[1] + v[2] + v[3];
        ss += v[0]*v[0] + v[1]*v[1] + v[2]*v[2] + v[3]*v[3];
    }
    for (int o = 32; o > 0; o >>= 1) { s += __shfl_down(s, o); ss += __shfl_down(ss, o); }
    __shared__ float red[8];
    int lane = t & 63, w = t >> 6;
    if (lane == 0) { red[w] = s; red[4 + w] = ss; }
    __syncthreads();
    if (t == 0) {
        float S  = red[0] + red[1] + red[2] + red[3];
        float SS = red[4] + red[5] + red[6] + red[7];
        float mean = S * (1.0f / 65536.0f);
        float var  = SS * (1.0f / 65536.0f) - mean * mean;
        stats[bg * 2]     = mean;
        stats[bg * 2 + 1] = rsqrtf(var + 1e-5f);
    }
}

// ------- normalize + transpose -> hT bf16 (BL x 512), packed-k layout -------
__global__ void k_norm_t(const float* __restrict__ x, const float* __restrict__ gamma,
                         const float* __restrict__ beta, const float* __restrict__ stats,
                         short* __restrict__ hT)
{
    __shared__ float tile[64 * 65];
    int b = blockIdx.z, c0 = blockIdx.y * 64, l0 = blockIdx.x * 64;
    int t = threadIdx.x;
    int lq = t & 15, cq = t >> 4;
    #pragma unroll
    for (int p = 0; p < 4; ++p) {
        int cl = cq + p * 16;
        int c = c0 + cl;
        float mean = stats[(b * 32 + (c >> 4)) * 2];
        float rstd = stats[(b * 32 + (c >> 4)) * 2 + 1];
        float a  = rstd * gamma[c];
        float bb = beta[c] - mean * a;
        f32x4 v = *(const f32x4*)(x + ((size_t)b << 21) + ((size_t)c << 12) + l0 + lq * 4);
        #pragma unroll
        for (int j = 0; j < 4; ++j) tile[cl * 65 + lq * 4 + j] = v[j] * a + bb;
    }
    __syncthreads();
    int ll = t >> 2, cq4 = t & 3;
    int bl = b * Ll + l0 + ll;
    short hbuf[16];
    #pragma unroll
    for (int j = 0; j < 16; ++j) hbuf[j] = f2bf(tile[(cq4 * 16 + j) * 65 + ll]);
    short* dst = hT + (size_t)bl * 512 + ((c0 >> 5) + (cq4 >> 1)) * 32 + ((cq4 & 1) << 2);
    #pragma unroll
    for (int jj = 0; jj < 4; ++jj) {
        s16x4 v4 = { hbuf[jj*4+0], hbuf[jj*4+1], hbuf[jj*4+2], hbuf[jj*4+3] };
        *(s16x4*)(dst + jj * 8) = v4;
    }
}

// ---------------- GEMM1 (flattened + fused logits, logits only in ntile==0) ----------------
__launch_bounds__(256, 2)
__global__ void k_gemm1f(const short* __restrict__ A, const short* __restrict__ Bw,
                         short* __restrict__ vbuf, short* __restrict__ lbuf)
{
    __shared__ short sA[2][8192];
    __shared__ short sB[2][8192];
    __shared__ short wqlds[8192];          // 16 rows x 512 k (rows 8-15 zero)
    const int t = threadIdx.x;
    const int nwg = 1024;
    const int bid = blockIdx.x;
    const int work = (bid & 7) * (nwg >> 3) + (bid >> 3);
    const int ntile = work & 3;
    const int n0 = ntile * 128;
    const int mbase = (work >> 2) * 512;

    const int lane = t & 63, wid = t >> 6;
    const int wm = wid >> 1, wn = wid & 1;
    const int g = lane >> 4, ln = lane & 15;

    // ---- preload wq panel (Wct rows 512..519) into LDS, swizzled ----
    {
        int row = t >> 5;                  // 0..7
        int cp = (t & 31) * 2;             // 16B-chunk index, +0/+1
        int4v v0 = *(const int4v*)(Bw + (size_t)(512 + row) * 512 + cp * 8);
        int4v v1 = *(const int4v*)(Bw + (size_t)(512 + row) * 512 + cp * 8 + 8);
        *(int4v*)((char*)wqlds + row * 1024 + ((cp * 16) ^ ((row & 7) << 4))) = v0;
        *(int4v*)((char*)wqlds + row * 1024 + (((cp + 1) * 16) ^ ((row & 7) << 4))) = v1;
        int4v z = {0, 0, 0, 0};
        int row2 = 8 + (t >> 5);
        *(int4v*)((char*)wqlds + row2 * 1024 + ((cp * 16) ^ ((row2 & 7) << 4))) = z;
        *(int4v*)((char*)wqlds + row2 * 1024 + (((cp + 1) * 16) ^ ((row2 & 7) << 4))) = z;
    }
    asm volatile("s_waitcnt vmcnt(0) lgkmcnt(0)" ::: "memory");
    BAR(); SFENCE();

    const int srow = wid * 8 + (lane >> 3);
    const int sinner = (((lane & 7) ^ ((lane >> 3) & 7)) << 3);
    const short* gAs = A  + (size_t)(mbase + srow) * 512 + sinner;
    const short* gBs = Bw + (size_t)(n0 + srow) * 512 + sinner;

    f32x4 acc[4][4] = {};
    f32x4 accq[4] = {};

    auto stage = [&](int kt, int buf) {
        size_t offA = (size_t)(kt >> 3) * 65536 + (size_t)(kt & 7) * 64;
        size_t offB = (size_t)(kt & 7) * 64;
        #pragma unroll
        for (int gq = 0; gq < 4; ++gq) {
            gload16(gAs + (size_t)gq * 32 * 512 + offA, &sA[buf][gq * 2048 + wid * 512]);
            gload16(gBs + (size_t)gq * 32 * 512 + offB, &sB[buf][gq * 2048 + wid * 512]);
        }
    };
    auto compute = [&](int buf, int kk) {
        #pragma unroll
        for (int ks = 0; ks < 2; ++ks) {
            short8 af[4], bfr[4];
            #pragma unroll
            for (int i = 0; i < 4; ++i) {
                af[i]  = *(const short8*)((const char*)&sA[buf][0] + swz_off(wm * 64 + i * 16 + ln, ks * 64 + g * 16));
                bfr[i] = *(const short8*)((const char*)&sB[buf][0] + swz_off(wn * 64 + i * 16 + ln, ks * 64 + g * 16));
            }
            #pragma unroll
            for (int mi = 0; mi < 4; ++mi)
                #pragma unroll
                for (int ni = 0; ni < 4; ++ni)
                    acc[mi][ni] = __builtin_amdgcn_mfma_f32_16x16x32_bf16(af[mi], bfr[ni], acc[mi][ni], 0, 0, 0);
            if (ntile == 0) {               // block-uniform: logits only where used
                short8 bq = *(const short8*)((const char*)wqlds + ln * 1024 +
                                      ((kk * 128 + ks * 64 + g * 16) ^ ((ln & 7) << 4)));
                #pragma unroll
                for (int mi = 0; mi < 4; ++mi)
                    accq[mi] = __builtin_amdgcn_mfma_f32_16x16x32_bf16(af[mi], bq, accq[mi], 0, 0, 0);
            }
        }
    };

    stage(0, 0); stage(1, 1);
    #pragma unroll 1
    for (int s = 0; s < 32; ++s) {
        if (s == 31)           asm volatile("s_waitcnt vmcnt(0)"  ::: "memory");
        else if ((s & 7) == 0 && s) asm volatile("s_waitcnt vmcnt(16)" ::: "memory");
        else                   asm volatile("s_waitcnt vmcnt(8)"  ::: "memory");
        BAR(); SFENCE();
        compute(s & 1, s & 7);
        SFENCE();
        if ((s & 7) == 7) {
            BAR();
            int m0 = mbase + (s >> 3) * 128;
            {
                short* scrW = &sB[s & 1][0] + wid * 2048;   // 4 KB per wave
                const int blkq = (lane & 7) >> 2, jq = lane & 3;
                #pragma unroll
                for (int p = 0; p < 2; ++p) {
                    #pragma unroll
                    for (int mh = 0; mh < 2; ++mh)
                        #pragma unroll
                        for (int ni = 0; ni < 4; ++ni)
                            #pragma unroll
                            for (int i = 0; i < 4; ++i)
                                scrW[(mh * 16 + g * 4 + i) * 64 + ni * 16 + ln] = f2bf(acc[p * 2 + mh][ni][i]);
                    asm volatile("s_waitcnt lgkmcnt(0)" ::: "memory"); SFENCE();
                    #pragma unroll
                    for (int it = 0; it < 4; ++it) {
                        int mrl = it * 8 + (lane >> 3);
                        const short* bp = scrW + mrl * 64 + blkq * 32;
                        s16x4 lo = *(const s16x4*)(bp + 4 * jq);
                        s16x4 hi = *(const s16x4*)(bp + 16 + 4 * jq);
                        union { int4v v; s16x4 h[2]; } ov;
                        ov.h[0] = lo; ov.h[1] = hi;
                        int m = m0 + wm * 64 + p * 32 + mrl;
                        int nc = n0 + wn * 64 + blkq * 32 + jq * 8;
                        *(int4v*)(vbuf + (size_t)m * 512 + nc) = ov.v;
                    }
                    asm volatile("s_waitcnt lgkmcnt(0)" ::: "memory"); SFENCE();
                }
            }
            if (ntile == 0 && wn == 0 && ln < 8) {
                #pragma unroll
                for (int mi = 0; mi < 4; ++mi)
                    #pragma unroll
                    for (int i = 0; i < 4; ++i) {
                        int m = m0 + wm * 64 + mi * 16 + g * 4 + i;
                        lbuf[(size_t)m * 8 + ln] = f2bf(accq[mi][i]);
                    }
            }
            #pragma unroll
            for (int mi = 0; mi < 4; ++mi) {
                #pragma unroll
                for (int ni = 0; ni < 4; ++ni)
                    acc[mi][ni] = (f32x4){0.f, 0.f, 0.f, 0.f};
                accq[mi] = (f32x4){0.f, 0.f, 0.f, 0.f};
            }
        }
        if (s < 30) { BAR(); stage(s + 2, s & 1); SFENCE(); }
    }
}

// ------- attn weights from lbuf: attnW[bl*32 + h*4 + j] = softmax_j -------
__global__ void k_attnw2(const short* __restrict__ lbuf, const float* __restrict__ rpe,
                         float* __restrict__ attnW)
{
    int tid = blockIdx.x * 256 + threadIdx.x;
    int bl = tid >> 3, h = tid & 7;
    int l = bl & (Ll - 1);
    float lg0 = (l > 0)      ? bf2f(lbuf[(size_t)(bl - 1) * 8 + h]) + rpe[h * 3 + 0] : -1e30f;
    float lg1 =                bf2f(lbuf[(size_t)bl * 8 + h])       + rpe[h * 3 + 1];
    float lg2 = (l < Ll - 1) ? bf2f(lbuf[(size_t)(bl + 1) * 8 + h]) + rpe[h * 3 + 2] : -1e30f;
    float m = fmaxf(lg1, fmaxf(lg0, lg2));
    float e0 = (l > 0)      ? __expf(lg0 - m) : 0.f;
    float e1 =                __expf(lg1 - m);
    float e2 = (l < Ll - 1) ? __expf(lg2 - m) : 0.f;
    float inv = 1.0f / (e0 + e1 + e2);
    f32x4 w = { e0 * inv, e1 * inv, e2 * inv, 0.0f };
    *(f32x4*)(attnW + (size_t)bl * 32 + h * 4) = w;
}

// ------- GEMM2 (flattened, FUSED combine, single-R early-reload pipeline) -------
// combineStep uses truncating pair-pack f32->bf16 (3 VALU/pair vs ~8 RNE).
__launch_bounds__(256, 2)
__global__ void k_gemm2f(const short* __restrict__ Wot, const short* __restrict__ vbuf,
                         const float* __restrict__ attnW, const float* __restrict__ x,
                         float* __restrict__ out)
{
    __shared__ short sA[2][8192];
    __shared__ short sBc[2][8192];
    __shared__ float wlds[4096];           // 128 rows x 8 hslots x 16B = 16 KB
    const int t = threadIdx.x;
    const int nwg = 1024;
    const int bid = blockIdx.x;
    const int work = (bid & 7) * (nwg >> 3) + (bid >> 3);
    const int n0 = work * 128;             // bl tile (fixed per block)

    const int lane = t & 63, wid = t >> 6;
    const int wm = wid >> 1, wn = wid & 1;
    const int g = lane >> 4, ln = lane & 15;

    const int srow = wid * 8 + (lane >> 3);                      // 0..31
    const int sinner = (((lane & 7) ^ ((lane >> 3) & 7)) << 3);  // shorts
    const short* gAs = Wot + (size_t)srow * 512 + sinner;

    // per-thread 3-row byte offsets for the 4 dest rows
    unsigned ovm[4], ov0[4], ovp[4];
    #pragma unroll
    for (int q2 = 0; q2 < 4; ++q2) {
        int r = n0 + srow + 32 * q2;
        int l = r & (Ll - 1);
        int rm = (l == 0) ? r : r - 1;
        int rp = (l == Ll - 1) ? r : r + 1;
        ov0[q2] = (unsigned)r  * 1024u + (unsigned)sinner * 2u;
        ovm[q2] = (unsigned)rm * 1024u + (unsigned)sinner * 2u;
        ovp[q2] = (unsigned)rp * 1024u + (unsigned)sinner * 2u;
    }
    const char* vb = (const char*)vbuf;

    // epilogue geometry
    const int r4 = lane >> 4, lcm = (lane & 15) * 4;
    const int ngE = n0 + wn * 64 + lcm;
    const size_t rowbase = ((size_t)(ngE >> 12) << 21) + (size_t)(ngE & (Ll - 1));
    const float* xrow = x + rowbase;
    float* outrow = out + rowbase;

    f32x4 acc[4][4] = {};
    U16 Rm[4], R0[4], Rp[4];       // single R set, reloaded right after consumption

    auto stageA = [&](int s, int buf) {
        size_t off = (size_t)(s >> 3) * 65536 + (size_t)(s & 7) * 64;
        #pragma unroll
        for (int gq = 0; gq < 4; ++gq)
            gload16(gAs + (size_t)gq * 32 * 512 + off, &sA[buf][gq * 2048 + wid * 512]);
    };
    auto loadR = [&](int s1) {
        unsigned off = (unsigned)(s1 & 7) * 128u;      // bytes
        #pragma unroll
        for (int q2 = 0; q2 < 4; ++q2) {
            Rm[q2].v = *(const int4v*)(vb + ovm[q2] + off);
            R0[q2].v = *(const int4v*)(vb + ov0[q2] + off);
            Rp[q2].v = *(const int4v*)(vb + ovp[q2] + off);
        }
    };
    auto combineStep = [&](int s1, int buf) {
        int h = s1 & 7;
        #pragma unroll
        for (int q2 = 0; q2 < 4; ++q2) {
            int r = srow + 32 * q2;
            f32x4 w = *(const f32x4*)&wlds[r * 32 + ((h ^ (r & 7)) << 2)];
            int4v cmv;
            #pragma unroll
            for (int jj = 0; jj < 4; ++jj) {
                float oa = w[0] * bf2f(Rm[q2].s[2 * jj])     + w[1] * bf2f(R0[q2].s[2 * jj])
                         + w[2] * bf2f(Rp[q2].s[2 * jj]);
                float ob = w[0] * bf2f(Rm[q2].s[2 * jj + 1]) + w[1] * bf2f(R0[q2].s[2 * jj + 1])
                         + w[2] * bf2f(Rp[q2].s[2 * jj + 1]);
                unsigned ua, ub;
                __builtin_memcpy(&ua, &oa, 4);
                __builtin_memcpy(&ub, &ob, 4);
                cmv[jj] = (int)((ub & 0xFFFF0000u) | (ua >> 16));   // truncating pack
            }
            *(int4v*)((char*)&sBc[buf][0] + q2 * 4096 + wid * 1024 + lane * 16) = cmv;
        }
    };
    auto compute = [&](int buf) {
        #pragma unroll
        for (int ks = 0; ks < 2; ++ks) {
            short8 af[4], bfr[4];
            #pragma unroll
            for (int i = 0; i < 4; ++i) {
                af[i]  = *(const short8*)((const char*)&sA[buf][0] + swz_off(wm * 64 + i * 16 + ln, ks * 64 + g * 16));
                bfr[i] = *(const short8*)((const char*)&sBc[buf][0] + swz_off(wn * 64 + i * 16 + ln, ks * 64 + g * 16));
            }
            #pragma unroll
            for (int mi = 0; mi < 4; ++mi)
                #pragma unroll
                for (int ni = 0; ni < 4; ++ni)
                    acc[mi][ni] = __builtin_amdgcn_mfma_f32_16x16x32_bf16(af[mi], bfr[ni], acc[mi][ni], 0, 0, 0);
        }
    };
    auto epilogue = [&](int s) {
        BAR();                                              // all waves done with sA[s&1]
        float* scr = (float*)((char*)&sA[s & 1][0] + wid * 4096);   // 16r x 64c f32
        int m0c = (s >> 3) * 128;
        #pragma unroll
        for (int p = 0; p < 4; ++p) {
            #pragma unroll
            for (int ni = 0; ni < 4; ++ni)
                #pragma unroll
                for (int i = 0; i < 4; ++i) {
                    int r = g * 4 + i;
                    int col = (ni * 16 + ln) ^ ((((r & 3) ^ (r >> 2)) & 3) << 4);
                    scr[r * 64 + col] = acc[p][ni][i];
                }
            asm volatile("s_waitcnt lgkmcnt(0)" ::: "memory"); SFENCE();
            #pragma unroll
            for (int j = 0; j < 4; ++j) {
                int rr = r4 + 4 * j;
                int cst = lcm ^ ((((rr & 3) ^ (rr >> 2)) & 3) << 4);
                f32x4 sv = *(const f32x4*)&scr[rr * 64 + cst];
                int c = m0c + wm * 64 + p * 16 + rr;
                f32x4 xv = *(const f32x4*)(xrow + ((size_t)c << 12));
                *(f32x4*)(outrow + ((size_t)c << 12)) = xv + sv;
            }
            asm volatile("s_waitcnt lgkmcnt(0)" ::: "memory"); SFENCE();
        }
        #pragma unroll
        for (int mi = 0; mi < 4; ++mi)
            #pragma unroll
            for (int ni = 0; ni < 4; ++ni)
                acc[mi][ni] = (f32x4){0.f, 0.f, 0.f, 0.f};
    };

    // ---- prologue: A(0),A(1),weights,R(0); drain; combine(0); R(1) ----
    stageA(0, 0); stageA(1, 1);
    {
        const float* wsrc = attnW + (size_t)n0 * 32;
        int rr = lane >> 3, hl = lane & 7;
        #pragma unroll
        for (int j = 0; j < 4; ++j) {
            int row = (wid * 4 + j) * 8 + rr;
            gload16f(wsrc + row * 32 + ((hl ^ (row & 7)) << 2), &wlds[(wid * 4 + j) * 256]);
        }
    }
    loadR(0); SFENCE();
    asm volatile("s_waitcnt vmcnt(0)" ::: "memory");
    BAR(); SFENCE();
    combineStep(0, 0);
    asm volatile("s_waitcnt lgkmcnt(0)" ::: "memory"); SFENCE();
    loadR(1); SFENCE();

    #pragma unroll 1
    for (int s = 0; s < 32; ++s) {
        if (s == 0 || s == 31)       asm volatile("s_waitcnt vmcnt(0)"  ::: "memory");
        else if ((s & 7) == 0)       asm volatile("s_waitcnt vmcnt(36)" ::: "memory");
        else                         asm volatile("s_waitcnt vmcnt(4)"  ::: "memory");
        BAR(); SFENCE();
        if (s < 31) {
            combineStep(s + 1, (s + 1) & 1);      // consume R(s+1)
            SFENCE();
            if (s < 30) { loadR(s + 2); SFENCE(); }   // reload same set, full-step flight
        }
        compute(s & 1);
        asm volatile("s_waitcnt lgkmcnt(0)" ::: "memory"); SFENCE();
        if ((s & 7) == 7) epilogue(s);
        if (s < 30) { BAR(); stageA(s + 2, s & 1); SFENCE(); }
    }
}

// ---------------- fallback path (ws too small; round-2-proven) ----------------
__launch_bounds__(256, 2)
__global__ void k_gemm1_fb(const short* __restrict__ A, const short* __restrict__ Bw,
                           short* __restrict__ kv)
{
    __shared__ short sA[2][8192];
    __shared__ short sB[2][8192];
    const int t = threadIdx.x;
    const int m0 = blockIdx.y * 128;
    const int n0 = blockIdx.x * 128;
    const int lane = t & 63, wid = t >> 6;
    const int wm = wid >> 1, wn = wid & 1;
    const int g = lane >> 4, ln = lane & 15;

    const int srow = wid * 8 + (lane >> 3);
    const int sinner = (((lane & 7) ^ ((lane >> 3) & 7)) << 3);
    const short* gAs = A  + (size_t)(m0 + srow) * 512 + sinner;
    const short* gBs = Bw + (size_t)(n0 + srow) * 512 + sinner;

    f32x4 acc[4][4] = {};

    auto stage = [&](int kt, int buf) {
        #pragma unroll
        for (int gq = 0; gq < 4; ++gq) {
            gload16(gAs + (size_t)gq * 32 * 512 + kt * 64, &sA[buf][gq * 2048 + wid * 512]);
            gload16(gBs + (size_t)gq * 32 * 512 + kt * 64, &sB[buf][gq * 2048 + wid * 512]);
        }
    };
    auto compute = [&](int buf) {
        #pragma unroll
        for (int ks = 0; ks < 2; ++ks) {
            short8 af[4], bfr[4];
            #pragma unroll
            for (int i = 0; i < 4; ++i) {
                af[i]  = *(const short8*)((const char*)&sA[buf][0] + swz_off(wm * 64 + i * 16 + ln, ks * 64 + g * 16));
                bfr[i] = *(const short8*)((const char*)&sB[buf][0] + swz_off(wn * 64 + i * 16 + ln, ks * 64 + g * 16));
            }
            #pragma unroll
            for (int mi = 0; mi < 4; ++mi)
                #pragma unroll
                for (int ni = 0; ni < 4; ++ni)
                    acc[mi][ni] = __builtin_amdgcn_mfma_f32_16x16x32_bf16(af[mi], bfr[ni], acc[mi][ni], 0, 0, 0);
        }
    };

    stage(0, 0);
    __syncthreads();
    #pragma unroll 1
    for (int kt = 0; kt < 8; ++kt) {
        if (kt < 7) stage(kt + 1, (kt + 1) & 1);
        compute(kt & 1);
        __syncthreads();
    }

    #pragma unroll
    for (int mi = 0; mi < 4; ++mi)
        #pragma unroll
        for (int ni = 0; ni < 4; ++ni) {
            int n = n0 + wn * 64 + ni * 16 + ln;
            if (n < NKV) {
                #pragma unroll
                for (int i = 0; i < 4; ++i) {
                    int m = m0 + wm * 64 + mi * 16 + g * 4 + i;
                    kv[(size_t)m * NKV + n] = f2bf(acc[mi][ni][i]);
                }
            }
        }
}

__global__ void k_attnw(const short* __restrict__ kv, const float* __restrict__ rpe,
                        float* __restrict__ attnW)
{
    int tid = blockIdx.x * 256 + threadIdx.x;
    int bl = tid >> 3, h = tid & 7;
    int l = bl & (Ll - 1);
    float lg[3];
    #pragma unroll
    for (int j = 0; j < 3; ++j) {
        bool valid = (j == 1) || (j == 0 && l > 0) || (j == 2 && l < Ll - 1);
        lg[j] = valid ? (bf2f(kv[(size_t)(bl + j - 1) * NKV + 512 + h]) + rpe[h * 3 + j])
                      : -1e30f;
    }
    float m = fmaxf(lg[0], fmaxf(lg[1], lg[2]));
    float e0 = __expf(lg[0] - m), e1 = __expf(lg[1] - m), e2 = __expf(lg[2] - m);
    float inv = 1.0f / (e0 + e1 + e2);
    f32x4 w = { e0 * inv, e1 * inv, e2 * inv, 0.0f };
    *(f32x4*)(attnW + (size_t)bl * 32 + h * 4) = w;
}

__launch_bounds__(256, 2)
__global__ void k_gemm2_fused(const short* __restrict__ Wot, const short* __restrict__ kv,
                              const float* __restrict__ attnW, const float* __restrict__ x,
                              float* __restrict__ out)
{
    __shared__ short sA[2][8192];
    __shared__ short sB[2][8192];
    const int t = threadIdx.x;
    const int m0 = blockIdx.x * 128;
    const int n0 = blockIdx.y * 128;
    const int lane = t & 63, wid = t >> 6;
    const int wm = wid >> 1, wn = wid & 1;
    const int g = lane >> 4, ln = lane & 15;
    const int sr = t >> 1, ksh = t & 1;

    const short* gA = Wot + (size_t)(m0 + sr) * 512 + ksh * 32;
    const int nrow = n0 + sr;
    const int lpos = nrow & (Ll - 1);
    const int nm1 = (lpos == 0) ? nrow : nrow - 1;
    const int np1 = (lpos == Ll - 1) ? nrow : nrow + 1;
    const short* gV0 = kv + (size_t)nrow * NKV + ksh * 32;
    const short* gVm = kv + (size_t)nm1  * NKV + ksh * 32;
    const short* gVp = kv + (size_t)np1  * NKV + ksh * 32;
    const float* gW = attnW + (size_t)nrow * 32;

    f32x4 acc[4][4] = {};
    U16 ra[4], rbm[4], rb0[4], rbp[4];
    f32x4 wv;

    auto load_tile = [&](int kt) {
        #pragma unroll
        for (int qq = 0; qq < 4; ++qq) {
            ra[qq].v  = *(const int4v*)(gA  + kt * 64 + qq * 8);
            rbm[qq].v = *(const int4v*)(gVm + kt * 64 + qq * 8);
            rb0[qq].v = *(const int4v*)(gV0 + kt * 64 + qq * 8);
            rbp[qq].v = *(const int4v*)(gVp + kt * 64 + qq * 8);
        }
        wv = *(const f32x4*)(gW + kt * 4);
    };
    auto write_tile = [&](int buf) {
        short ob[32];
        #pragma unroll
        for (int qq = 0; qq < 4; ++qq)
            #pragma unroll
            for (int j = 0; j < 8; ++j) {
                float o = wv[0] * bf2f(rbm[qq].s[j]) + wv[1] * bf2f(rb0[qq].s[j])
                        + wv[2] * bf2f(rbp[qq].s[j]);
                ob[qq * 8 + j] = f2bf(o);
            }
        #pragma unroll
        for (int f = 0; f < 4; ++f) {
            U16 wa, wb;
            #pragma unroll
            for (int j = 0; j < 4; ++j) {
                wa.s[j]     = ra[f >> 1].s[(f & 1) * 4 + j];
                wa.s[4 + j] = ra[2 + (f >> 1)].s[(f & 1) * 4 + j];
                wb.s[j]     = ob[4 * f + j];
                wb.s[4 + j] = ob[16 + 4 * f + j];
            }
            int off = swz_off(sr, ksh * 64 + f * 16);
            *(int4v*)((char*)&sA[buf][0] + off) = wa.v;
            *(int4v*)((char*)&sB[buf][0] + off) = wb.v;
        }
    };
    auto compute = [&](int buf) {
        #pragma unroll
        for (int ks = 0; ks < 2; ++ks) {
            short8 af[4], bfr[4];
            #pragma unroll
            for (int i = 0; i < 4; ++i) {
                af[i]  = *(const short8*)((const char*)&sA[buf][0] + swz_off(wm * 64 + i * 16 + ln, ks * 64 + g * 16));
                bfr[i] = *(const short8*)((const char*)&sB[buf][0] + swz_off(wn * 64 + i * 16 + ln, ks * 64 + g * 16));
            }
            #pragma unroll
            for (int mi = 0; mi < 4; ++mi)
                #pragma unroll
                for (int ni = 0; ni < 4; ++ni)
                    acc[mi][ni] = __builtin_amdgcn_mfma_f32_16x16x32_bf16(af[mi], bfr[ni], acc[mi][ni], 0, 0, 0);
        }
    };

    load_tile(0); write_tile(0); __syncthreads();
    #pragma unroll 1
    for (int kt = 0; kt < 8; ++kt) {
        if (kt < 7) load_tile(kt + 1);
        compute(kt & 1);
        if (kt < 7) write_tile((kt + 1) & 1);
        __syncthreads();
    }

    #pragma unroll
    for (int mi = 0; mi < 4; ++mi)
        #pragma unroll
        for (int ni = 0; ni < 4; ++ni)
            #pragma unroll
            for (int i = 0; i < 4; ++i) {
                int c = m0 + wm * 64 + mi * 16 + g * 4 + i;
                int ng = n0 + wn * 64 + ni * 16 + ln;
                int b = ng >> 12, l = ng & (Ll - 1);
                size_t off = ((size_t)b << 21) | ((size_t)c << 12) | (size_t)l;
                out[off] = x[off] + acc[mi][ni][i];
            }
}

// ---------------- launcher ----------------
extern "C" void kernel_launch(void* const* d_in, const int* in_sizes, int n_in,
                              void* d_out, int out_size, void* d_ws, size_t ws_size,
                              hipStream_t stream)
{
    const float* x     = (const float*)d_in[0];
    const float* gamma = (const float*)d_in[1];
    const float* beta  = (const float*)d_in[2];
    const float* Wk    = (const float*)d_in[3];
    const float* Wv    = (const float*)d_in[4];
    const float* Wo    = (const float*)d_in[5];
    const float* q     = (const float*)d_in[6];
    const float* rpe   = (const float*)d_in[7];
    float* out = (float*)d_out;
    char* ws = (char*)d_ws;

    const size_t MB128 = 134217728ull;
    const size_t MAIN_WS = MB128 * 2 + 655360 + 524288 + 2097152 + 8192;

    if (ws_size >= MAIN_WS) {
        float* attnW = (float*)(ws);                       // 16 MB
        short* vbuf  = (short*)(ws + MB128);
        short* Wct   = (short*)(ws + 2 * MB128);
        short* Wot   = (short*)(ws + 2 * MB128 + 655360);
        short* lbuf  = (short*)(ws + 2 * MB128 + 655360 + 524288);
        float* stats = (float*)(ws + 2 * MB128 + 655360 + 524288 + 2097152);
        short* hT    = (short*)d_out;          // scratch until gemm1 done

        k_prep<<<1152, 64, 0, stream>>>(Wk, Wv, Wo, q, Wct, Wot, 1);
        k_stats<<<1024, 256, 0, stream>>>(x, stats);
        k_norm_t<<<dim3(64, 8, 32), 256, 0, stream>>>(x, gamma, beta, stats, hT);
        k_gemm1f<<<1024, 256, 0, stream>>>(hT, Wct, vbuf, lbuf);
        k_attnw2<<<4096, 256, 0, stream>>>(lbuf, rpe, attnW);
        k_gemm2f<<<1024, 256, 0, stream>>>(Wot, vbuf, attnW, x, out);
    } else {
        short* Wct   = (short*)(ws + 0);
        short* Wot   = (short*)(ws + 655360);
        float* stats = (float*)(ws + 1179648);
        float* attnW = (float*)(ws + 1187840);
        short* kv    = (short*)(ws + 17965056);
        short* hT    = (short*)d_out;

        k_prep<<<1152, 64, 0, stream>>>(Wk, Wv, Wo, q, Wct, Wot, 0);
        k_stats<<<1024, 256, 0, stream>>>(x, stats);
        k_norm_t<<<dim3(64, 8, 32), 256, 0, stream>>>(x, gamma, beta, stats, hT);
        k_gemm1_fb<<<dim3(5, 1024), 256, 0, stream>>>(hT, Wct, kv);
        k_attnw<<<4096, 256, 0, stream>>>(kv, rpe, attnW);
        k_gemm2_fused<<<dim3(4, 1024), 256, 0, stream>>>(Wot, kv, attnW, x, out);
    }
}